// Round 8
// baseline (15988.451 us; speedup 1.0000x reference)
//
#include <hip/hip_runtime.h>
#include <math.h>

// Problem constants
#define Bb    64
#define Ss    1024
#define CINc  256
#define Hh    512
#define Kk    768          // CIN + H
#define NBLK  256          // one block per CU; each owns 2 hidden units (8 gate rows)
#define NTHR  512          // 8 waves; thread (bb=tid>>3, sub=tid&7): batch bb, k-slice sub
#define SLOTS 8            // 4 gates x 2 units
#define WSTRIDE 6144       // floats of w per block (x region 2048 + h region 4096)

// ws layout: [wt: NBLK*WSTRIDE f32][hbuf16: 2*B*H halves][ctr: 8 x 64B]
#define WT_FLOATS   (NBLK * WSTRIDE)
#define HBUF_HALVES (2 * Bb * Hh)
#define NCTR 8
#define CTR_STRIDE 16      // uints -> 64 B apart (separate cache lines)

// Extract center-tap weights.
// x region (k<256): granule g=k>>2 (4 k), float4 f=2*(k&3)+(s>>2),
//   dst = bl*W + 32*g + 4*(f ^ (g&7)) + (s&3).
// h region (k>=256): kh=k-256, granule G=kh>>3 (8 k), kk=kh&7, f=2*kk+(s>>2),
//   dst = bl*W + 2048 + 64*G + 4*(f ^ (G&7)) + (s&3).
// Reader sub touches granules with (g&7|G&7)==sub -> XOR makes banks conflict-free.
__global__ void extract_weights(const float* __restrict__ W, float* __restrict__ wt) {
    int total = NBLK * Kk * SLOTS;
    for (int idx = blockIdx.x * blockDim.x + threadIdx.x; idx < total;
         idx += gridDim.x * blockDim.x) {
        int s    = idx & 7;
        int k    = (idx >> 3) % Kk;
        int bl   = idx / (Kk * SLOTS);
        int col  = 2 * bl + (s & 1) + Hh * (s >> 1);
        int dst;
        if (k < CINc) {
            int g = k >> 2;
            int f = ((k & 3) << 1) | (s >> 2);
            dst = bl * WSTRIDE + (g << 5) + (((f ^ (g & 7)) << 2) | (s & 3));
        } else {
            int kh = k - CINc;
            int G  = kh >> 3;
            int kk = kh & 7;
            int f  = (kk << 1) | (s >> 2);
            dst = bl * WSTRIDE + 2048 + (G << 6) + (((f ^ (G & 7)) << 2) | (s & 3));
        }
        wt[dst] = W[((size_t)col * Kk + k) * 3 + 1];
    }
}

__device__ __forceinline__ float sigf(float v) { return 1.0f / (1.0f + expf(-v)); }

__device__ __forceinline__ void wait_vm0() {
    asm volatile("s_waitcnt vmcnt(0)" ::: "memory");
}
__device__ __forceinline__ void wait_vm4() {
    asm volatile("s_waitcnt vmcnt(4)" ::: "memory");
    __builtin_amdgcn_sched_barrier(0);
}
__device__ __forceinline__ uint4 load4u_llc(const void* p) {
    uint4 v;
    asm volatile("global_load_dwordx4 %0, %1, off sc0 sc1" : "=&v"(v) : "v"(p));
    return v;
}
__device__ __forceinline__ float4 load4_glb(const float* p) {
    float4 v;
    asm volatile("global_load_dwordx4 %0, %1, off" : "=&v"(v) : "v"(p));
    return v;
}
__device__ __forceinline__ void store_llc_h16(unsigned short* p, float v) {
    _Float16 h = (_Float16)v;
    union { _Float16 h; unsigned short u; } c; c.h = h;
    unsigned int uv = c.u;
    asm volatile("global_store_short %0, %1, off sc0 sc1" :: "v"(p), "v"(uv) : "memory");
}

// dword pair of halves -> 2 floats (static indexing only)
__device__ __forceinline__ void cvt2(unsigned int d, float& a0, float& a1) {
    union { unsigned int u; _Float16 h[2]; } c; c.u = d;
    a0 = (float)c.h[0]; a1 = (float)c.h[1];
}

// x-part granule (4 k) x 8 slots = 32 FMAs from 8 pre-XORed float4 pointers.
__device__ __forceinline__ void gfma(const float4* const* wq, int fo, float4 av, float* acc) {
    float4 a0 = wq[0][fo], b0 = wq[1][fo];
    float4 a1 = wq[2][fo], b1 = wq[3][fo];
    float4 a2 = wq[4][fo], b2 = wq[5][fo];
    float4 a3 = wq[6][fo], b3 = wq[7][fo];
    acc[0] = fmaf(av.x, a0.x, acc[0]); acc[1] = fmaf(av.x, a0.y, acc[1]);
    acc[2] = fmaf(av.x, a0.z, acc[2]); acc[3] = fmaf(av.x, a0.w, acc[3]);
    acc[4] = fmaf(av.x, b0.x, acc[4]); acc[5] = fmaf(av.x, b0.y, acc[5]);
    acc[6] = fmaf(av.x, b0.z, acc[6]); acc[7] = fmaf(av.x, b0.w, acc[7]);
    acc[0] = fmaf(av.y, a1.x, acc[0]); acc[1] = fmaf(av.y, a1.y, acc[1]);
    acc[2] = fmaf(av.y, a1.z, acc[2]); acc[3] = fmaf(av.y, a1.w, acc[3]);
    acc[4] = fmaf(av.y, b1.x, acc[4]); acc[5] = fmaf(av.y, b1.y, acc[5]);
    acc[6] = fmaf(av.y, b1.z, acc[6]); acc[7] = fmaf(av.y, b1.w, acc[7]);
    acc[0] = fmaf(av.z, a2.x, acc[0]); acc[1] = fmaf(av.z, a2.y, acc[1]);
    acc[2] = fmaf(av.z, a2.z, acc[2]); acc[3] = fmaf(av.z, a2.w, acc[3]);
    acc[4] = fmaf(av.z, b2.x, acc[4]); acc[5] = fmaf(av.z, b2.y, acc[5]);
    acc[6] = fmaf(av.z, b2.z, acc[6]); acc[7] = fmaf(av.z, b2.w, acc[7]);
    acc[0] = fmaf(av.w, a3.x, acc[0]); acc[1] = fmaf(av.w, a3.y, acc[1]);
    acc[2] = fmaf(av.w, a3.z, acc[2]); acc[3] = fmaf(av.w, a3.w, acc[3]);
    acc[4] = fmaf(av.w, b3.x, acc[4]); acc[5] = fmaf(av.w, b3.y, acc[5]);
    acc[6] = fmaf(av.w, b3.z, acc[6]); acc[7] = fmaf(av.w, b3.w, acc[7]);
}

// h-part granule (8 k, fp16 raw uint4) using 16 pre-XORed pointers + imm offset.
__device__ __forceinline__ void hfma(const float4* const* wE, const float4* const* wO,
                                     int mo, uint4 r, float* acc) {
    float a0,a1,a2,a3,a4,a5,a6,a7;
    cvt2(r.x, a0, a1); cvt2(r.y, a2, a3); cvt2(r.z, a4, a5); cvt2(r.w, a6, a7);
    #pragma unroll
    for (int kk = 0; kk < 8; ++kk) {
        float av = (kk==0)?a0:(kk==1)?a1:(kk==2)?a2:(kk==3)?a3:
                   (kk==4)?a4:(kk==5)?a5:(kk==6)?a6:a7;
        float4 wlo = wE[kk][mo];
        float4 whi = wO[kk][mo];
        acc[0] = fmaf(av, wlo.x, acc[0]); acc[1] = fmaf(av, wlo.y, acc[1]);
        acc[2] = fmaf(av, wlo.z, acc[2]); acc[3] = fmaf(av, wlo.w, acc[3]);
        acc[4] = fmaf(av, whi.x, acc[4]); acc[5] = fmaf(av, whi.y, acc[5]);
        acc[6] = fmaf(av, whi.z, acc[6]); acc[7] = fmaf(av, whi.w, acc[7]);
    }
}

__global__ __launch_bounds__(NTHR, 2) void lstm_coop(
    const float* __restrict__ x,    // [B,S,CIN]
    const float* __restrict__ bias, // [4H]
    const float* __restrict__ h0,   // [B,H]
    const float* __restrict__ c0,   // [B,H]
    const float* __restrict__ wt,   // [NBLK][WSTRIDE] swizzled
    unsigned short* __restrict__ hbuf16, // [2][B][H] fp16 (LLC-coherent access only)
    unsigned* ctr,                  // 8 striped barrier counters
    float* __restrict__ out)        // [B,S,H] ++ [B,H] ++ [B,H]
{
    __shared__ float w_lds[WSTRIDE];       // 24 KB
    __shared__ float g_par[8 * 516];       // 16.1 KB, [sub][slot*64 + bb]

    const int tid  = threadIdx.x;
    const int lane = tid & 63;
    const int q    = __builtin_amdgcn_readfirstlane(tid >> 6);  // wave 0..7
    const int bl   = blockIdx.x;
    const int u0   = 2 * bl;
    const int bb   = tid >> 3;     // batch row
    const int sub  = tid & 7;      // k-slice

    // ---- stage this block's weights into LDS once ----
    {
        const float4* wsrc = (const float4*)(wt + (size_t)bl * WSTRIDE);
        float4* wdst = (float4*)w_lds;
        for (int i = tid; i < WSTRIDE / 4; i += NTHR) wdst[i] = wsrc[i];
    }
    // x region: 8 pre-XORed pointers; granule j: offset 64*j (float4s).
    const float4* wqs4[8];
    #pragma unroll
    for (int i = 0; i < 8; ++i)
        wqs4[i] = ((const float4*)w_lds) + (i ^ sub) + 8 * sub;
    // h region: 16 pre-XORed pointers (even=slots0-3, odd=slots4-7); granule m: +128*m.
    const float4* whE[8];
    const float4* whO[8];
    #pragma unroll
    for (int kk = 0; kk < 8; ++kk) {
        whE[kk] = ((const float4*)w_lds) + 512 + 16 * sub + (((2 * kk)     ) ^ sub);
        whO[kk] = ((const float4*)w_lds) + 512 + 16 * sub + (((2 * kk) + 1 ) ^ sub);
    }

    // ---- init hbuf16[0] = fp16(h0) with LLC-coherent stores ----
    for (int i = bl * NTHR + tid; i < Bb * Hh; i += NBLK * NTHR)
        store_llc_h16(&hbuf16[i], h0[i]);
    wait_vm0();

    float cstate = 0.f;
    int   ucell  = 0;
    float bi = 0.f, bf = 0.f, bg = 0.f, bo = 0.f;
    if (q < 2) {
        ucell  = u0 + q;
        cstate = c0[(size_t)lane * Hh + ucell];
        bi = bias[ucell];
        bf = bias[ucell + Hh];
        bg = bias[ucell + 2 * Hh];
        bo = bias[ucell + 3 * Hh];
    }

    __syncthreads();
    // ---- barrier phase 1 arrival ----
    if (tid == 0) __hip_atomic_fetch_add(&ctr[(bl & 7) * CTR_STRIDE], 1u,
                                         __ATOMIC_RELAXED, __HIP_MEMORY_SCOPE_AGENT);

    // ---- x-part prologue for t=0 (hidden under barrier settle) ----
    const float* xrow_base = x + (size_t)bb * Ss * CINc + 4 * sub;
    float  accx[SLOTS];
    {
        float4 xv[8];
        #pragma unroll
        for (int j = 0; j < 8; ++j) xv[j] = load4_glb(xrow_base + 32 * j);   // t=0
        wait_vm0();
        __builtin_amdgcn_sched_barrier(0);
        #pragma unroll
        for (int s = 0; s < SLOTS; ++s) accx[s] = 0.f;
        #pragma unroll
        for (int j = 0; j < 8; ++j) gfma(wqs4, 64 * j, xv[j], accx);
    }

    if (tid < NCTR) {
        while (__hip_atomic_load(&ctr[tid * CTR_STRIDE],
                                 __ATOMIC_RELAXED, __HIP_MEMORY_SCOPE_AGENT) < 32u)
            __builtin_amdgcn_s_sleep(2);
    }
    __atomic_signal_fence(__ATOMIC_SEQ_CST);
    __syncthreads();

    for (int t = 0; t < Ss; ++t) {
        const int cur = t & 1;
        // thread reads halves [8*(sub+8m) .. +8) of row bb: byte 16*sub + 128*m
        const char* hrow = (const char*)(hbuf16 + (size_t)cur * Bb * Hh
                                         + (size_t)bb * Hh) + 16 * sub;
        unsigned short* hnxt = hbuf16 + (size_t)(cur ^ 1) * Bb * Hh;

        uint4 hr[8];
        #pragma unroll
        for (int m = 0; m < 8; ++m) hr[m] = load4u_llc(hrow + 128 * m);

        float acc[SLOTS];
        #pragma unroll
        for (int s = 0; s < SLOTS; ++s) acc[s] = accx[s];

        wait_vm4();   // hr[0..3] landed (in-order retirement)
        #pragma unroll
        for (int m = 0; m < 4; ++m) hfma(whE, whO, 128 * m, hr[m], acc);

        wait_vm0();   // hr[4..7] landed
        __builtin_amdgcn_sched_barrier(0);
        #pragma unroll
        for (int m = 4; m < 8; ++m) hfma(whE, whO, 128 * m, hr[m], acc);

        // ---- gate partial reduction via LDS ----
        #pragma unroll
        for (int s = 0; s < SLOTS; ++s) g_par[sub * 516 + s * 64 + bb] = acc[s];
        asm volatile("s_waitcnt lgkmcnt(0)" ::: "memory");
        __builtin_amdgcn_sched_barrier(0);
        __builtin_amdgcn_s_barrier();
        asm volatile("" ::: "memory");

        if (q < 2) {   // waves 0,1: cell update for units u0+q, batch = lane
            float s0 = 0.f, s1 = 0.f, s2 = 0.f, s3 = 0.f;
            #pragma unroll
            for (int w = 0; w < 8; ++w) {
                s0 += g_par[w * 516 + (0 + q) * 64 + lane];   // gate i
                s1 += g_par[w * 516 + (2 + q) * 64 + lane];   // gate f
                s2 += g_par[w * 516 + (4 + q) * 64 + lane];   // gate g
                s3 += g_par[w * 516 + (6 + q) * 64 + lane];   // gate o
            }
            float iv = sigf(s0 + bi);
            float fv = sigf(s1 + bf);
            float gv = tanhf(s2 + bg);
            float ov = sigf(s3 + bo);
            cstate = fv * cstate + iv * gv;
            float hv_ = ov * tanhf(cstate);
            store_llc_h16(&hnxt[(size_t)lane * Hh + ucell], hv_);   // fp16 publish
            out[((size_t)lane * Ss + t) * Hh + ucell] = hv_;
            if (t == Ss - 1) {
                out[(size_t)Bb * Ss * Hh + (size_t)lane * Hh + ucell] = hv_;
                out[(size_t)Bb * Ss * Hh + (size_t)Bb * Hh + (size_t)lane * Hh + ucell] = cstate;
            }
        }
        wait_vm0();        // drain h publish + out stores
        __builtin_amdgcn_s_barrier();
        asm volatile("" ::: "memory");

        // ---- grid barrier arrival, phase t+2 ----
        if (tid == 0) __hip_atomic_fetch_add(&ctr[(bl & 7) * CTR_STRIDE], 1u,
                                             __ATOMIC_RELAXED, __HIP_MEMORY_SCOPE_AGENT);

        // ---- settle window: load x(t+1) from warm L2 and do the x-GEMM ----
        {
            const int tn = (t + 1) & (Ss - 1);   // t=Ss-1 wraps (result unused)
            const float* xrow = xrow_base + (size_t)tn * CINc;
            float4 xv[8];
            #pragma unroll
            for (int j = 0; j < 8; ++j) xv[j] = load4_glb(xrow + 32 * j);
            wait_vm0();
            __builtin_amdgcn_sched_barrier(0);
            #pragma unroll
            for (int s = 0; s < SLOTS; ++s) accx[s] = 0.f;
            #pragma unroll
            for (int j = 0; j < 8; ++j) gfma(wqs4, 64 * j, xv[j], accx);
        }

        const unsigned target = 32u * (unsigned)(t + 2);
        if (tid < NCTR) {
            while (__hip_atomic_load(&ctr[tid * CTR_STRIDE],
                                     __ATOMIC_RELAXED, __HIP_MEMORY_SCOPE_AGENT) < target)
                __builtin_amdgcn_s_sleep(2);
        }
        __atomic_signal_fence(__ATOMIC_SEQ_CST);
        __builtin_amdgcn_s_barrier();
        asm volatile("" ::: "memory");
    }
}

extern "C" void kernel_launch(void* const* d_in, const int* in_sizes, int n_in,
                              void* d_out, int out_size, void* d_ws, size_t ws_size,
                              hipStream_t stream) {
    const float* x    = (const float*)d_in[0];
    const float* W    = (const float*)d_in[1];
    const float* bias = (const float*)d_in[2];
    const float* h0   = (const float*)d_in[3];
    const float* c0   = (const float*)d_in[4];
    float* out = (float*)d_out;

    float*          wt     = (float*)d_ws;
    unsigned short* hbuf16 = (unsigned short*)(wt + WT_FLOATS);
    unsigned*       ctr    = (unsigned*)(hbuf16 + HBUF_HALVES);

    hipMemsetAsync(ctr, 0, NCTR * CTR_STRIDE * sizeof(unsigned), stream);
    extract_weights<<<256, 256, 0, stream>>>(W, wt);

    void* args[] = { (void*)&x, (void*)&bias, (void*)&h0, (void*)&c0,
                     (void*)&wt, (void*)&hbuf16, (void*)&ctr, (void*)&out };
    hipLaunchCooperativeKernel((const void*)lstm_coop, dim3(NBLK), dim3(NTHR),
                               args, 0, stream);
}

// Round 9
// 8674.976 us; speedup vs baseline: 1.8431x; 1.8431x over previous
//
#include <hip/hip_runtime.h>
#include <math.h>

// Problem constants
#define Bb    64
#define Ss    1024
#define CINc  256
#define Hh    512
#define Kk    768          // CIN + H
#define NBLK  256          // one block per CU; each owns 2 hidden units (8 gate rows)
#define NTHR  512          // 8 waves; thread (kg=tid&31, bg=tid>>5): k-slice kg, batches 4bg..4bg+3
#define SLOTS 8            // 4 gates x 2 units
#define WSTRIDE 6144       // floats of w per block, (chunk,i,half)-grouped conflict-free layout

// ws layout: [wt: NBLK*WSTRIDE f32][hbuf: 2*B*H f32][ctr: 8 x 64B]
#define WT_FLOATS   (NBLK * WSTRIDE)
#define HBUF_FLOATS (2 * Bb * Hh)
#define NCTR 8
#define CTR_STRIDE 16      // uints -> 64 B apart (separate cache lines)

// Extract center-tap weights into (chunk,i,half,kg)-grouped layout:
// k: chunk c=k>>7, i=(k>>5)&3, kg=k&31; slot s: half h=s>>2, elem s&3.
// float4 index = c*256 + (2*i+h)*32 + kg  -> 32 lanes (kg) read 512 contiguous B.
__global__ void extract_weights(const float* __restrict__ W, float* __restrict__ wt) {
    int total = NBLK * Kk * SLOTS;
    for (int idx = blockIdx.x * blockDim.x + threadIdx.x; idx < total;
         idx += gridDim.x * blockDim.x) {
        int s    = idx & 7;
        int k    = (idx >> 3) % Kk;
        int bl   = idx / (Kk * SLOTS);
        int col  = 2 * bl + (s & 1) + Hh * (s >> 1);   // unit=s&1, gate=s>>1 (i,f,g,o)
        int c    = k >> 7;
        int i    = (k >> 5) & 3;
        int kg   = k & 31;
        int f4   = c * 256 + (2 * i + (s >> 2)) * 32 + kg;
        wt[(size_t)bl * WSTRIDE + f4 * 4 + (s & 3)] = W[((size_t)col * Kk + k) * 3 + 1];
    }
}

__device__ __forceinline__ float sigf(float v) { return 1.0f / (1.0f + expf(-v)); }

__device__ __forceinline__ void wait_vm0() {
    asm volatile("s_waitcnt vmcnt(0)" ::: "memory");
}
__device__ __forceinline__ void wait_vm4() {
    asm volatile("s_waitcnt vmcnt(4)" ::: "memory");
    __builtin_amdgcn_sched_barrier(0);
}
__device__ __forceinline__ void lds_fence_barrier() {
    asm volatile("s_waitcnt lgkmcnt(0)" ::: "memory");
    __builtin_amdgcn_sched_barrier(0);
    __builtin_amdgcn_s_barrier();
    asm volatile("" ::: "memory");
}
__device__ __forceinline__ void plain_barrier() {
    __builtin_amdgcn_s_barrier();
    asm volatile("" ::: "memory");
}
__device__ __forceinline__ float4 load4_llc(const float* p) {
    float4 v;
    asm volatile("global_load_dwordx4 %0, %1, off sc0 sc1" : "=&v"(v) : "v"(p));
    return v;
}
__device__ __forceinline__ float4 load4_glb(const float* p) {
    float4 v;
    asm volatile("global_load_dwordx4 %0, %1, off" : "=&v"(v) : "v"(p));
    return v;
}
__device__ __forceinline__ void store_llc(float* p, float v) {
    asm volatile("global_store_dword %0, %1, off sc0 sc1" :: "v"(p), "v"(v) : "memory");
}

__global__ __launch_bounds__(NTHR, 2) void lstm_coop(
    const float* __restrict__ x,    // [B,S,CIN]
    const float* __restrict__ bias, // [4H]
    const float* __restrict__ h0,   // [B,H]
    const float* __restrict__ c0,   // [B,H]
    const float* __restrict__ wt,   // [NBLK][WSTRIDE]
    float* __restrict__ hbuf,       // [2][B][H]  (LLC-coherent access only)
    unsigned* ctr,                  // 8 striped barrier counters
    float* __restrict__ out)        // [B,S,H] ++ [B,H] ++ [B,H]
{
    // a_buf: one 128-k chunk [64 b][128 k] (32 KB) + headroom; after the GEMM it is
    // reused as parA[16 kg][517] for the k-partial reduction (33.1 KB <= 33.8 KB).
    __shared__ float a_buf[8448];          // 33 KB
    __shared__ float w_lds[WSTRIDE];       // 24 KB
    __shared__ float g_final[Bb * 9 + 8];  // 2.3 KB, [b][9] padded (bank-free)

    const int tid  = threadIdx.x;
    const int lane = tid & 63;
    const int q    = __builtin_amdgcn_readfirstlane(tid >> 6);  // wave 0..7
    const int bl   = blockIdx.x;
    const int u0   = 2 * bl;
    const int kg   = tid & 31;     // k-residue: this thread handles k = kg + 32*i
    const int bg   = tid >> 5;     // batch group: batches 4bg .. 4bg+3

    // ---- stage this block's weights into LDS once ----
    {
        const float4* wsrc = (const float4*)(wt + (size_t)bl * WSTRIDE);
        float4* wdst = (float4*)w_lds;
        for (int i = tid; i < WSTRIDE / 4; i += NTHR) wdst[i] = wsrc[i];
    }
    const float4* wk = ((const float4*)w_lds) + kg;   // lane-contiguous w reads

    // a-read bases: a_buf dword (4bg+bl')*128 + kg + 32*i  (bank = kg: conflict-free)
    int ab0 = (4 * bg + 0) * 128 + kg;
    int ab1 = (4 * bg + 1) * 128 + kg;
    int ab2 = (4 * bg + 2) * 128 + kg;
    int ab3 = (4 * bg + 3) * 128 + kg;

    // staging map: thread copies float4 fi = tid + 512j (j 0..3) of the chunk;
    // fi -> row b = fi>>5, f4-in-row r = fi&31. Coalesced loads, b128 LDS writes.
    const int sb = tid >> 5;            // NOTE: same as bg; row base for j=0
    const int sr = tid & 31;

    // ---- init hbuf[0] = h0 with LLC-coherent stores ----
    for (int i = bl * NTHR + tid; i < Bb * Hh; i += NBLK * NTHR) store_llc(&hbuf[i], h0[i]);
    wait_vm0();

    float cstate = 0.f;
    int   ucell  = 0;
    float bi = 0.f, bf = 0.f, bg_ = 0.f, bo = 0.f;
    if (q < 2) {
        ucell  = u0 + q;
        cstate = c0[(size_t)lane * Hh + ucell];
        bi  = bias[ucell];
        bf  = bias[ucell + Hh];
        bg_ = bias[ucell + 2 * Hh];
        bo  = bias[ucell + 3 * Hh];
    }

    __syncthreads();
    // ---- barrier phase 1 arrival ----
    if (tid == 0) __hip_atomic_fetch_add(&ctr[(bl & 7) * CTR_STRIDE], 1u,
                                         __ATOMIC_RELAXED, __HIP_MEMORY_SCOPE_AGENT);

    float acc[32];   // [bl'][slot]

    // ===== x-part (chunks 0,1) for t=0: staged + GEMMed under barrier settle =====
    {
        float4 xv[8];
        #pragma unroll
        for (int j = 0; j < 8; ++j) {
            int fi = tid + 512 * (j & 3);
            int b  = fi >> 5, r = fi & 31;
            int c  = j >> 2;
            xv[j] = load4_glb(x + (size_t)b * Ss * CINc + 0 * CINc + c * 128 + 4 * r);
        }
        #pragma unroll
        for (int v = 0; v < 32; ++v) acc[v] = 0.f;
        wait_vm4();
        #pragma unroll
        for (int j = 0; j < 4; ++j) ((float4*)a_buf)[tid + 512 * j] = xv[j];
        lds_fence_barrier();
        #pragma unroll
        for (int i = 0; i < 4; ++i) {          // GEMM chunk 0
            float4 wlo = wk[0 * 256 + 64 * i];
            float4 whi = wk[0 * 256 + 64 * i + 32];
            float a0 = a_buf[ab0 + 32 * i], a1 = a_buf[ab1 + 32 * i];
            float a2 = a_buf[ab2 + 32 * i], a3 = a_buf[ab3 + 32 * i];
            #define FMA8(BL, AV) \
                acc[BL*8+0] = fmaf(AV, wlo.x, acc[BL*8+0]); \
                acc[BL*8+1] = fmaf(AV, wlo.y, acc[BL*8+1]); \
                acc[BL*8+2] = fmaf(AV, wlo.z, acc[BL*8+2]); \
                acc[BL*8+3] = fmaf(AV, wlo.w, acc[BL*8+3]); \
                acc[BL*8+4] = fmaf(AV, whi.x, acc[BL*8+4]); \
                acc[BL*8+5] = fmaf(AV, whi.y, acc[BL*8+5]); \
                acc[BL*8+6] = fmaf(AV, whi.z, acc[BL*8+6]); \
                acc[BL*8+7] = fmaf(AV, whi.w, acc[BL*8+7]);
            FMA8(0, a0) FMA8(1, a1) FMA8(2, a2) FMA8(3, a3)
        }
        plain_barrier();
        wait_vm0();
        #pragma unroll
        for (int j = 0; j < 4; ++j) ((float4*)a_buf)[tid + 512 * j] = xv[4 + j];
        lds_fence_barrier();
        #pragma unroll
        for (int i = 0; i < 4; ++i) {          // GEMM chunk 1
            float4 wlo = wk[1 * 256 + 64 * i];
            float4 whi = wk[1 * 256 + 64 * i + 32];
            float a0 = a_buf[ab0 + 32 * i], a1 = a_buf[ab1 + 32 * i];
            float a2 = a_buf[ab2 + 32 * i], a3 = a_buf[ab3 + 32 * i];
            FMA8(0, a0) FMA8(1, a1) FMA8(2, a2) FMA8(3, a3)
        }
    }

    if (tid < NCTR) {
        while (__hip_atomic_load(&ctr[tid * CTR_STRIDE],
                                 __ATOMIC_RELAXED, __HIP_MEMORY_SCOPE_AGENT) < 32u)
            __builtin_amdgcn_s_sleep(2);
    }
    __atomic_signal_fence(__ATOMIC_SEQ_CST);
    __syncthreads();

    for (int t = 0; t < Ss; ++t) {
        const int cur = t & 1;
        const float* hcur = hbuf + (size_t)cur * Bb * Hh;
        float*       hnxt = hbuf + (size_t)(cur ^ 1) * Bb * Hh;

        // h source addresses for this thread's 4 staged float4s (per chunk offset)
        const float* hsrc = hcur + (size_t)sb * Hh + 4 * sr;   // j-row step adds 16*Hh

        float4 hv[8];
        // issue chunks 2,3 (8 LLC loads)
        #pragma unroll
        for (int j = 0; j < 4; ++j) hv[j]     = load4_llc(hsrc + (size_t)16 * Hh * j + 0 * 128);
        #pragma unroll
        for (int j = 0; j < 4; ++j) hv[4 + j] = load4_llc(hsrc + (size_t)16 * Hh * j + 1 * 128);

        plain_barrier();               // settle-GEMM a-reads done everywhere (reuse safe)
        wait_vm4();                    // chunk 2 landed
        #pragma unroll
        for (int j = 0; j < 4; ++j) ((float4*)a_buf)[tid + 512 * j] = hv[j];
        lds_fence_barrier();
        // issue chunk 4, GEMM chunk 2
        #pragma unroll
        for (int j = 0; j < 4; ++j) hv[j] = load4_llc(hsrc + (size_t)16 * Hh * j + 2 * 128);
        #pragma unroll
        for (int i = 0; i < 4; ++i) {
            float4 wlo = wk[2 * 256 + 64 * i];
            float4 whi = wk[2 * 256 + 64 * i + 32];
            float a0 = a_buf[ab0 + 32 * i], a1 = a_buf[ab1 + 32 * i];
            float a2 = a_buf[ab2 + 32 * i], a3 = a_buf[ab3 + 32 * i];
            FMA8(0, a0) FMA8(1, a1) FMA8(2, a2) FMA8(3, a3)
        }
        plain_barrier();
        wait_vm4();                    // chunk 3 landed (chunk 4 in flight)
        #pragma unroll
        for (int j = 0; j < 4; ++j) ((float4*)a_buf)[tid + 512 * j] = hv[4 + j];
        lds_fence_barrier();
        // issue chunk 5, GEMM chunk 3
        #pragma unroll
        for (int j = 0; j < 4; ++j) hv[4 + j] = load4_llc(hsrc + (size_t)16 * Hh * j + 3 * 128);
        #pragma unroll
        for (int i = 0; i < 4; ++i) {
            float4 wlo = wk[3 * 256 + 64 * i];
            float4 whi = wk[3 * 256 + 64 * i + 32];
            float a0 = a_buf[ab0 + 32 * i], a1 = a_buf[ab1 + 32 * i];
            float a2 = a_buf[ab2 + 32 * i], a3 = a_buf[ab3 + 32 * i];
            FMA8(0, a0) FMA8(1, a1) FMA8(2, a2) FMA8(3, a3)
        }
        plain_barrier();
        wait_vm4();                    // chunk 4 landed (chunk 5 in flight)
        #pragma unroll
        for (int j = 0; j < 4; ++j) ((float4*)a_buf)[tid + 512 * j] = hv[j];
        lds_fence_barrier();
        #pragma unroll
        for (int i = 0; i < 4; ++i) {  // GEMM chunk 4
            float4 wlo = wk[4 * 256 + 64 * i];
            float4 whi = wk[4 * 256 + 64 * i + 32];
            float a0 = a_buf[ab0 + 32 * i], a1 = a_buf[ab1 + 32 * i];
            float a2 = a_buf[ab2 + 32 * i], a3 = a_buf[ab3 + 32 * i];
            FMA8(0, a0) FMA8(1, a1) FMA8(2, a2) FMA8(3, a3)
        }
        plain_barrier();
        wait_vm0();                    // chunk 5 landed
        #pragma unroll
        for (int j = 0; j < 4; ++j) ((float4*)a_buf)[tid + 512 * j] = hv[4 + j];
        lds_fence_barrier();
        #pragma unroll
        for (int i = 0; i < 4; ++i) {  // GEMM chunk 5
            float4 wlo = wk[5 * 256 + 64 * i];
            float4 whi = wk[5 * 256 + 64 * i + 32];
            float a0 = a_buf[ab0 + 32 * i], a1 = a_buf[ab1 + 32 * i];
            float a2 = a_buf[ab2 + 32 * i], a3 = a_buf[ab3 + 32 * i];
            FMA8(0, a0) FMA8(1, a1) FMA8(2, a2) FMA8(3, a3)
        }

        // ---- k-reduction: butterfly over kg^16 (in-wave), then LDS tree over 16 ----
        #pragma unroll
        for (int v = 0; v < 32; ++v) {
            float o = __int_as_float(
                __builtin_amdgcn_ds_swizzle(__float_as_int(acc[v]), 0x401F)); // xor 16
            acc[v] += o;
        }
        plain_barrier();               // all a_buf GEMM reads done -> overlay as parA
        if (kg < 16) {
            #pragma unroll
            for (int bl2 = 0; bl2 < 4; ++bl2)
                #pragma unroll
                for (int s = 0; s < 8; ++s)
                    a_buf[kg * 517 + (4 * bg + bl2) * 8 + s] = acc[bl2 * 8 + s];
        }
        lds_fence_barrier();
        {   // final sum: thread (s=tid&7, b=tid>>3) reduces 16 partials
            const int fs_s = tid & 7, fs_b = tid >> 3;
            float sum = 0.f;
            #pragma unroll
            for (int k16 = 0; k16 < 16; ++k16)
                sum += a_buf[k16 * 517 + fs_b * 8 + fs_s];
            g_final[fs_b * 9 + fs_s] = sum;
        }
        lds_fence_barrier();

        if (q < 2) {   // waves 0,1: cell update for units u0+q, batch = lane
            float iv = sigf(g_final[lane * 9 + 0 + q] + bi);
            float fv = sigf(g_final[lane * 9 + 2 + q] + bf);
            float gv = tanhf(g_final[lane * 9 + 4 + q] + bg_);
            float ov = sigf(g_final[lane * 9 + 6 + q] + bo);
            cstate = fv * cstate + iv * gv;
            float hv_ = ov * tanhf(cstate);
            store_llc(&hnxt[(size_t)lane * Hh + ucell], hv_);   // coherent publish
            out[((size_t)lane * Ss + t) * Hh + ucell] = hv_;
            if (t == Ss - 1) {
                out[(size_t)Bb * Ss * Hh + (size_t)lane * Hh + ucell] = hv_;
                out[(size_t)Bb * Ss * Hh + (size_t)Bb * Hh + (size_t)lane * Hh + ucell] = cstate;
            }
        }
        wait_vm0();        // drain publish + out stores
        plain_barrier();

        // ---- grid barrier arrival, phase t+2 ----
        if (tid == 0) __hip_atomic_fetch_add(&ctr[(bl & 7) * CTR_STRIDE], 1u,
                                             __ATOMIC_RELAXED, __HIP_MEMORY_SCOPE_AGENT);

        // ---- settle window: stage + GEMM x chunks 0,1 for step t+1 ----
        {
            const int tn = (t + 1) & (Ss - 1);   // t=Ss-1 wraps (result unused)
            float4 xv[8];
            #pragma unroll
            for (int j = 0; j < 8; ++j) {
                int fi = tid + 512 * (j & 3);
                int b  = fi >> 5, r = fi & 31;
                int c  = j >> 2;
                xv[j] = load4_glb(x + (size_t)b * Ss * CINc + (size_t)tn * CINc
                                  + c * 128 + 4 * r);
            }
            #pragma unroll
            for (int v = 0; v < 32; ++v) acc[v] = 0.f;
            wait_vm4();
            #pragma unroll
            for (int j = 0; j < 4; ++j) ((float4*)a_buf)[tid + 512 * j] = xv[j];
            lds_fence_barrier();
            #pragma unroll
            for (int i = 0; i < 4; ++i) {
                float4 wlo = wk[0 * 256 + 64 * i];
                float4 whi = wk[0 * 256 + 64 * i + 32];
                float a0 = a_buf[ab0 + 32 * i], a1 = a_buf[ab1 + 32 * i];
                float a2 = a_buf[ab2 + 32 * i], a3 = a_buf[ab3 + 32 * i];
                FMA8(0, a0) FMA8(1, a1) FMA8(2, a2) FMA8(3, a3)
            }
            plain_barrier();
            wait_vm0();
            #pragma unroll
            for (int j = 0; j < 4; ++j) ((float4*)a_buf)[tid + 512 * j] = xv[4 + j];
            lds_fence_barrier();
            #pragma unroll
            for (int i = 0; i < 4; ++i) {
                float4 wlo = wk[1 * 256 + 64 * i];
                float4 whi = wk[1 * 256 + 64 * i + 32];
                float a0 = a_buf[ab0 + 32 * i], a1 = a_buf[ab1 + 32 * i];
                float a2 = a_buf[ab2 + 32 * i], a3 = a_buf[ab3 + 32 * i];
                FMA8(0, a0) FMA8(1, a1) FMA8(2, a2) FMA8(3, a3)
            }
        }

        const unsigned target = 32u * (unsigned)(t + 2);
        if (tid < NCTR) {
            while (__hip_atomic_load(&ctr[tid * CTR_STRIDE],
                                     __ATOMIC_RELAXED, __HIP_MEMORY_SCOPE_AGENT) < target)
                __builtin_amdgcn_s_sleep(2);
        }
        __atomic_signal_fence(__ATOMIC_SEQ_CST);
        plain_barrier();
    }
}

extern "C" void kernel_launch(void* const* d_in, const int* in_sizes, int n_in,
                              void* d_out, int out_size, void* d_ws, size_t ws_size,
                              hipStream_t stream) {
    const float* x    = (const float*)d_in[0];
    const float* W    = (const float*)d_in[1];
    const float* bias = (const float*)d_in[2];
    const float* h0   = (const float*)d_in[3];
    const float* c0   = (const float*)d_in[4];
    float* out = (float*)d_out;

    float*    wt   = (float*)d_ws;
    float*    hbuf = wt + WT_FLOATS;
    unsigned* ctr  = (unsigned*)(hbuf + HBUF_FLOATS);

    hipMemsetAsync(ctr, 0, NCTR * CTR_STRIDE * sizeof(unsigned), stream);
    extract_weights<<<256, 256, 0, stream>>>(W, wt);

    void* args[] = { (void*)&x, (void*)&bias, (void*)&h0, (void*)&c0,
                     (void*)&wt, (void*)&hbuf, (void*)&ctr, (void*)&out };
    hipLaunchCooperativeKernel((const void*)lstm_coop, dim3(NBLK), dim3(NTHR),
                               args, 0, stream);
}